// Round 12
// baseline (596.951 us; speedup 1.0000x reference)
//
#include <hip/hip_runtime.h>
#include <stdint.h>

// Problem: B=64, DIM=512, T=2048, S=1024.
// out[b][s][t] = softmax_s( 2*cross - msq[s] ),  cross = sum_d units[d][s]*H[b][d][t].
// Pipeline:
//   k_prep_units: units fp32 -> Upack hi/lo (MFMA-fragment-slab order) + msq[s].
//   k_prep_h:     H fp32 -> Bpack hi/lo (fragment-slab order per (b, t-group-64)).
//   k_fused:      FULL-S GEMM (1024s x 64t per block; wave tile 64s x 64t),
//                 mfma_f32_32x32x16_bf16, 3-term hi/lo.  16 waves (1024 thr),
//                 acc[2][2]=64 AGPR + 32 operand VGPR -> <=128 regs/wave ->
//                 4 waves/SIMD (TLP latency hiding; the lever never tried).
//                 B: full 128KB panel staged in prologue (one vmcnt(0)+barrier),
//                 K-loop barrier-free: 4 ds_read + 8 A-loads + 12 MFMA per slab.
//                 In-register softmax epilogue (8KB LDS reductions).
// ws: BpackH[0,128M) BpackL[128M,256M) UpackH(1M) UpackL(1M) msq(4K) => ~258 MB.

typedef unsigned short u16;
typedef __attribute__((ext_vector_type(8))) short short8;    // 8 x bf16 (4 VGPR)
typedef __attribute__((ext_vector_type(4))) float f32x4;
typedef __attribute__((ext_vector_type(16))) float f32x16;   // 32x32 C/D

#define B_DIM 64
#define DIM   512
#define T_DIM 2048
#define S_DIM 1024

// k_fused LDS map
#define B_LO_O 65536
#define REDM_O 131072        // [16][64] floats = 4KB
#define REDS_O 135168
#define SM_SZ  139264

__device__ __forceinline__ u16 f32_to_bf16(float f) {
  uint32_t u = __float_as_uint(f);
  uint32_t r = u + 0x7FFFu + ((u >> 16) & 1u);   // RNE
  return (u16)(r >> 16);
}
__device__ __forceinline__ float bf16_to_f32(u16 h) {
  return __uint_as_float(((uint32_t)h) << 16);
}

// ---------------- K0a: units -> Upack hi/lo + msq ----------------
__global__ __launch_bounds__(256) void k_prep_units(const float* __restrict__ units,
                                                    u16* __restrict__ UpH, u16* __restrict__ UpL,
                                                    float* __restrict__ msq) {
  const int s0 = blockIdx.x * 4;
  const int tid = threadIdx.x;
  const int lane = tid & 63, wv = tid >> 6;
  float acc0 = 0.f, acc1 = 0.f, acc2 = 0.f, acc3 = 0.f;
#pragma unroll
  for (int j = 0; j < 2; ++j) {
    const int d = tid + j * 256;
    const float4 v = *(const float4*)(units + (size_t)d * S_DIM + s0);
    acc0 += v.x * v.x; acc1 += v.y * v.y; acc2 += v.z * v.z; acc3 += v.w * v.w;
    const int dbase = (d >> 4) * 16384 + ((d >> 3) & 1) * 256 + (d & 7);
    const float fv[4] = {v.x, v.y, v.z, v.w};
#pragma unroll
    for (int q = 0; q < 4; ++q) {
      const int s = s0 + q;
      const int idx = dbase + ((s >> 5) * 64 + (s & 31)) * 8;
      const u16 h = f32_to_bf16(fv[q]);
      UpH[idx] = h;
      UpL[idx] = f32_to_bf16(fv[q] - bf16_to_f32(h));
    }
  }
#pragma unroll
  for (int off = 1; off < 64; off <<= 1) {
    acc0 += __shfl_xor(acc0, off);
    acc1 += __shfl_xor(acc1, off);
    acc2 += __shfl_xor(acc2, off);
    acc3 += __shfl_xor(acc3, off);
  }
  __shared__ float part[4][4];
  if (lane == 0) { part[wv][0] = acc0; part[wv][1] = acc1; part[wv][2] = acc2; part[wv][3] = acc3; }
  __syncthreads();
  if (tid < 4) msq[s0 + tid] = part[0][tid] + part[1][tid] + part[2][tid] + part[3][tid];
}

// ---------------- K0b: H [b][d][t] -> Bpack hi/lo ----------------
__global__ __launch_bounds__(256) void k_prep_h(const float* __restrict__ H,
                                                u16* __restrict__ BpH, u16* __restrict__ BpL) {
  __shared__ float tile[64 * 68];
  const int bx = blockIdx.x;                 // t-group (64 t)
  const int d0 = blockIdx.y * 64;
  const int b = blockIdx.z;
  const int t0 = bx * 64;
  const int tid = threadIdx.x;
#pragma unroll
  for (int j = 0; j < 4; ++j) {
    const int chunk = tid + j * 256;
    const int r = chunk >> 4, c4 = (chunk & 15) * 4;
    const float4 v = *(const float4*)(H + ((size_t)(b * DIM + d0 + r)) * T_DIM + t0 + c4);
    *(float4*)(&tile[r * 68 + c4]) = v;
  }
  __syncthreads();
#pragma unroll
  for (int j = 0; j < 2; ++j) {
    const int chunk = tid + j * 256;
    const int q = chunk >> 3, e8 = (chunk & 7) * 8;   // t-local q, d-local group e8
    union { u16 us[8]; uint4 v4; } hi, lo;
#pragma unroll
    for (int k = 0; k < 8; ++k) {
      const float f = tile[(e8 + k) * 68 + q];
      const u16 h = f32_to_bf16(f);
      hi.us[k] = h;
      lo.us[k] = f32_to_bf16(f - bf16_to_f32(h));
    }
    const int dg = d0 + e8;
    const int chunkB = (q >> 5) * 64 + ((dg >> 3) & 1) * 32 + (q & 31);
    const size_t o = ((((size_t)b * 32 + bx) * 32 + (dg >> 4)) * 128 + chunkB) * 8;
    *(uint4*)(BpH + o) = hi.v4;
    *(uint4*)(BpL + o) = lo.v4;
  }
}

// ---------------- K1: fused GEMM (32x32x16) + softmax, 16 waves ----------------
__device__ __forceinline__ void gl16(const void* g, void* l) {
  __builtin_amdgcn_global_load_lds((const __attribute__((address_space(1))) void*)g,
                                   (__attribute__((address_space(3))) void*)l, 16, 0, 0);
}

#define WAITV0() asm volatile("s_waitcnt vmcnt(0)" ::: "memory")
#define SYNCPT() do { __builtin_amdgcn_s_barrier(); __builtin_amdgcn_sched_barrier(0); } while (0)

__global__ __launch_bounds__(1024, 4) void k_fused(const u16* __restrict__ UpH, const u16* __restrict__ UpL,
                                                   const u16* __restrict__ BpH, const u16* __restrict__ BpL,
                                                   const float* __restrict__ msq,
                                                   float* __restrict__ out) {
  __shared__ __align__(16) char sm[SM_SZ];
  const int tid = threadIdx.x;
  const int lane = tid & 63, wv = tid >> 6;       // wv 0..15
  const int l31 = lane & 31, lhi = lane >> 5;
  const int sw = wv;                              // wave owns s rows [sw*64, +64) = tiles 2sw, 2sw+1

  const int tgx = blockIdx.x;                     // 64-t group
  const int t00 = tgx * 64;
  const int bb = blockIdx.y;

  // ---- A: direct-from-global fragment bases (verified layout) ----
  // byte = ks*32768 + (2*sw + mt)*1024 + lane*16
  const char* const aH = (const char*)UpH + sw * 2048 + lane * 16;
  const char* const aL = (const char*)UpL + sw * 2048 + lane * 16;
  // ---- B: block panel (64KB hi + 64KB lo), staged whole in prologue ----
  const size_t bgBase = (size_t)(bb * 32 + tgx) * 65536;
  const char* const pBH = (const char*)BpH + bgBase;
  const char* const pBL = (const char*)BpL + bgBase;

  // ---- prologue: stage full B panel (8 gl_lds per thread) ----
#pragma unroll
  for (int r = 0; r < 4; ++r) {
    const int off = (tid + r * 1024) * 16;        // [0, 65536)
    gl16(pBH + off, sm + off);
  }
#pragma unroll
  for (int r = 0; r < 4; ++r) {
    const int off = (tid + r * 1024) * 16;
    gl16(pBL + off, sm + B_LO_O + off);
  }

  f32x16 acc[2][2];
#pragma unroll
  for (int mt = 0; mt < 2; ++mt)
#pragma unroll
    for (int nt = 0; nt < 2; ++nt)
#pragma unroll
      for (int r = 0; r < 16; ++r)
        acc[mt][nt][r] = 0.f;

  WAITV0();
  SYNCPT();                                       // B panel resident in LDS

  // ---- K-loop: barrier-free, TLP-hidden ----
#pragma unroll 1
  for (int ks = 0; ks < 32; ++ks) {
    const int bo = ks * 2048 + lane * 16;
    short8 bh0 = *(const short8*)(sm + bo);
    short8 bh1 = *(const short8*)(sm + bo + 1024);
    short8 bl0 = *(const short8*)(sm + B_LO_O + bo);
    short8 bl1 = *(const short8*)(sm + B_LO_O + bo + 1024);
    const size_t ko = (size_t)ks << 15;
    short8 ah0 = *(const short8*)(aH + ko);
    short8 ah1 = *(const short8*)(aH + ko + 1024);
    short8 al0 = *(const short8*)(aL + ko);
    short8 al1 = *(const short8*)(aL + ko + 1024);
    __builtin_amdgcn_s_setprio(1);
    acc[0][0] = __builtin_amdgcn_mfma_f32_32x32x16_bf16(ah0, bh0, acc[0][0], 0, 0, 0);
    acc[0][1] = __builtin_amdgcn_mfma_f32_32x32x16_bf16(ah0, bh1, acc[0][1], 0, 0, 0);
    acc[1][0] = __builtin_amdgcn_mfma_f32_32x32x16_bf16(ah1, bh0, acc[1][0], 0, 0, 0);
    acc[1][1] = __builtin_amdgcn_mfma_f32_32x32x16_bf16(ah1, bh1, acc[1][1], 0, 0, 0);
    acc[0][0] = __builtin_amdgcn_mfma_f32_32x32x16_bf16(ah0, bl0, acc[0][0], 0, 0, 0);
    acc[0][1] = __builtin_amdgcn_mfma_f32_32x32x16_bf16(ah0, bl1, acc[0][1], 0, 0, 0);
    acc[1][0] = __builtin_amdgcn_mfma_f32_32x32x16_bf16(ah1, bl0, acc[1][0], 0, 0, 0);
    acc[1][1] = __builtin_amdgcn_mfma_f32_32x32x16_bf16(ah1, bl1, acc[1][1], 0, 0, 0);
    acc[0][0] = __builtin_amdgcn_mfma_f32_32x32x16_bf16(al0, bh0, acc[0][0], 0, 0, 0);
    acc[0][1] = __builtin_amdgcn_mfma_f32_32x32x16_bf16(al0, bh1, acc[0][1], 0, 0, 0);
    acc[1][0] = __builtin_amdgcn_mfma_f32_32x32x16_bf16(al1, bh0, acc[1][0], 0, 0, 0);
    acc[1][1] = __builtin_amdgcn_mfma_f32_32x32x16_bf16(al1, bh1, acc[1][1], 0, 0, 0);
    __builtin_amdgcn_s_setprio(0);
  }

  // ---- epilogue: softmax over s, in registers ----
  // s = sw*64 + mt*32 + lhi*4 + q*8 + r (reg=q*4+r); t = t00 + nt*32 + l31.
  float* redM = (float*)(sm + REDM_O);   // [16][64]
  float* redS = (float*)(sm + REDS_O);
  float mx0 = -3.0e38f, mx1 = -3.0e38f;
#pragma unroll
  for (int mt = 0; mt < 2; ++mt) {
    const int sb = sw * 64 + mt * 32 + lhi * 4;
#pragma unroll
    for (int q = 0; q < 4; ++q) {
      const f32x4 mq = *(const f32x4*)(msq + sb + q * 8);
#pragma unroll
      for (int r = 0; r < 4; ++r) {
        const int reg = q * 4 + r;
        const float v0 = 2.f * acc[mt][0][reg] - mq[r];
        const float v1 = 2.f * acc[mt][1][reg] - mq[r];
        acc[mt][0][reg] = v0; acc[mt][1][reg] = v1;
        mx0 = fmaxf(mx0, v0); mx1 = fmaxf(mx1, v1);
      }
    }
  }
  mx0 = fmaxf(mx0, __shfl_xor(mx0, 32));
  mx1 = fmaxf(mx1, __shfl_xor(mx1, 32));
  if (lane < 32) { redM[wv * 64 + l31] = mx0; redM[wv * 64 + 32 + l31] = mx1; }
  __syncthreads();
  float M0 = redM[l31], M1 = redM[32 + l31];
#pragma unroll
  for (int w = 1; w < 16; ++w) {
    M0 = fmaxf(M0, redM[w * 64 + l31]);
    M1 = fmaxf(M1, redM[w * 64 + 32 + l31]);
  }
  float s0 = 0.f, s1 = 0.f;
#pragma unroll
  for (int mt = 0; mt < 2; ++mt)
#pragma unroll
    for (int reg = 0; reg < 16; ++reg) {
      const float e0 = __expf(acc[mt][0][reg] - M0);
      const float e1 = __expf(acc[mt][1][reg] - M1);
      acc[mt][0][reg] = e0; acc[mt][1][reg] = e1;
      s0 += e0; s1 += e1;
    }
  s0 += __shfl_xor(s0, 32);
  s1 += __shfl_xor(s1, 32);
  if (lane < 32) { redS[wv * 64 + l31] = s0; redS[wv * 64 + 32 + l31] = s1; }
  __syncthreads();
  float S0 = redS[l31], S1 = redS[32 + l31];
#pragma unroll
  for (int w = 1; w < 16; ++w) {
    S0 += redS[w * 64 + l31];
    S1 += redS[w * 64 + 32 + l31];
  }
  const float r0 = 1.0f / S0, r1 = 1.0f / S1;

  float* const outb = out + ((size_t)bb << 21);   // b * 1024 * 2048
  const int tc0 = t00 + l31, tc1 = t00 + 32 + l31;
#pragma unroll
  for (int mt = 0; mt < 2; ++mt) {
    const int sb = sw * 64 + mt * 32 + lhi * 4;
#pragma unroll
    for (int q = 0; q < 4; ++q)
#pragma unroll
      for (int r = 0; r < 4; ++r) {
        const int srow = sb + q * 8 + r;
        const int reg = q * 4 + r;
        outb[(size_t)srow * T_DIM + tc0] = acc[mt][0][reg] * r0;
        outb[(size_t)srow * T_DIM + tc1] = acc[mt][1][reg] * r1;
      }
  }
}

// ---------------- launch ----------------
extern "C" void kernel_launch(void* const* d_in, const int* in_sizes, int n_in,
                              void* d_out, int out_size, void* d_ws, size_t ws_size,
                              hipStream_t stream) {
  (void)in_sizes; (void)n_in; (void)out_size; (void)ws_size;
  const float* H = (const float*)d_in[0];
  const float* units = (const float*)d_in[1];
  float* out = (float*)d_out;
  char* ws = (char*)d_ws;
  u16* BpH = (u16*)(ws);
  u16* BpL = (u16*)(ws + 134217728);
  u16* UpH = (u16*)(ws + 268435456);
  u16* UpL = (u16*)(ws + 269484032);
  float* msq = (float*)(ws + 270532608);

  k_prep_units<<<dim3(S_DIM / 4), 256, 0, stream>>>(units, UpH, UpL, msq);
  k_prep_h<<<dim3(T_DIM / 64, DIM / 64, B_DIM), 256, 0, stream>>>(H, BpH, BpL);
  k_fused<<<dim3(T_DIM / 64, B_DIM), 1024, 0, stream>>>(UpH, UpL, BpH, BpL, msq, out);
}

// Round 13
// 588.522 us; speedup vs baseline: 1.0143x; 1.0143x over previous
//
#include <hip/hip_runtime.h>
#include <stdint.h>

// Problem: B=64, DIM=512, T=2048, S=1024.
// out[b][s][t] = softmax_s( 2*cross - msq[s] ),  cross = sum_d units[d][s]*H[b][d][t].
// Pipeline:
//   k_prep_units: units fp32 -> Upack hi/lo (MFMA-fragment-slab order) + msq[s].
//   k_prep_h:     H fp32 -> Bpack hi/lo (fragment-slab order per (b, t-group-64)).
//   k_fused:      FULL-S GEMM (1024s x 64t per block; wave tile 64s x 64t),
//                 mfma_f32_32x32x16_bf16, 3-term hi/lo.  16 waves (1024 thr),
//                 4 waves/SIMD (<=128 unified regs enforced by block size).
//                 R13: A register DOUBLE-BUFFER (even/odd sets, issued after the
//                 set's last use -> ~1550 cyc prefetch distance over the ~600 cyc
//                 loaded-L2 latency). B: full 128KB panel staged in prologue
//                 (one vmcnt(0)+barrier), single-buffered ds_reads per slab
//                 (120 cyc lgkm absorbed by 4-wave pipe slack). Barrier-free loop.
//                 In-register softmax epilogue (8KB LDS reductions).
// ws: BpackH[0,128M) BpackL[128M,256M) UpackH(1M) UpackL(1M) msq(4K) => ~258 MB.

typedef unsigned short u16;
typedef __attribute__((ext_vector_type(8))) short short8;    // 8 x bf16 (4 VGPR)
typedef __attribute__((ext_vector_type(4))) float f32x4;
typedef __attribute__((ext_vector_type(16))) float f32x16;   // 32x32 C/D

#define B_DIM 64
#define DIM   512
#define T_DIM 2048
#define S_DIM 1024

// k_fused LDS map
#define B_LO_O 65536
#define REDM_O 131072        // [16][64] floats = 4KB
#define REDS_O 135168
#define SM_SZ  139264

__device__ __forceinline__ u16 f32_to_bf16(float f) {
  uint32_t u = __float_as_uint(f);
  uint32_t r = u + 0x7FFFu + ((u >> 16) & 1u);   // RNE
  return (u16)(r >> 16);
}
__device__ __forceinline__ float bf16_to_f32(u16 h) {
  return __uint_as_float(((uint32_t)h) << 16);
}

// ---------------- K0a: units -> Upack hi/lo + msq ----------------
__global__ __launch_bounds__(256) void k_prep_units(const float* __restrict__ units,
                                                    u16* __restrict__ UpH, u16* __restrict__ UpL,
                                                    float* __restrict__ msq) {
  const int s0 = blockIdx.x * 4;
  const int tid = threadIdx.x;
  const int lane = tid & 63, wv = tid >> 6;
  float acc0 = 0.f, acc1 = 0.f, acc2 = 0.f, acc3 = 0.f;
#pragma unroll
  for (int j = 0; j < 2; ++j) {
    const int d = tid + j * 256;
    const float4 v = *(const float4*)(units + (size_t)d * S_DIM + s0);
    acc0 += v.x * v.x; acc1 += v.y * v.y; acc2 += v.z * v.z; acc3 += v.w * v.w;
    const int dbase = (d >> 4) * 16384 + ((d >> 3) & 1) * 256 + (d & 7);
    const float fv[4] = {v.x, v.y, v.z, v.w};
#pragma unroll
    for (int q = 0; q < 4; ++q) {
      const int s = s0 + q;
      const int idx = dbase + ((s >> 5) * 64 + (s & 31)) * 8;
      const u16 h = f32_to_bf16(fv[q]);
      UpH[idx] = h;
      UpL[idx] = f32_to_bf16(fv[q] - bf16_to_f32(h));
    }
  }
#pragma unroll
  for (int off = 1; off < 64; off <<= 1) {
    acc0 += __shfl_xor(acc0, off);
    acc1 += __shfl_xor(acc1, off);
    acc2 += __shfl_xor(acc2, off);
    acc3 += __shfl_xor(acc3, off);
  }
  __shared__ float part[4][4];
  if (lane == 0) { part[wv][0] = acc0; part[wv][1] = acc1; part[wv][2] = acc2; part[wv][3] = acc3; }
  __syncthreads();
  if (tid < 4) msq[s0 + tid] = part[0][tid] + part[1][tid] + part[2][tid] + part[3][tid];
}

// ---------------- K0b: H [b][d][t] -> Bpack hi/lo ----------------
__global__ __launch_bounds__(256) void k_prep_h(const float* __restrict__ H,
                                                u16* __restrict__ BpH, u16* __restrict__ BpL) {
  __shared__ float tile[64 * 68];
  const int bx = blockIdx.x;                 // t-group (64 t)
  const int d0 = blockIdx.y * 64;
  const int b = blockIdx.z;
  const int t0 = bx * 64;
  const int tid = threadIdx.x;
#pragma unroll
  for (int j = 0; j < 4; ++j) {
    const int chunk = tid + j * 256;
    const int r = chunk >> 4, c4 = (chunk & 15) * 4;
    const float4 v = *(const float4*)(H + ((size_t)(b * DIM + d0 + r)) * T_DIM + t0 + c4);
    *(float4*)(&tile[r * 68 + c4]) = v;
  }
  __syncthreads();
#pragma unroll
  for (int j = 0; j < 2; ++j) {
    const int chunk = tid + j * 256;
    const int q = chunk >> 3, e8 = (chunk & 7) * 8;   // t-local q, d-local group e8
    union { u16 us[8]; uint4 v4; } hi, lo;
#pragma unroll
    for (int k = 0; k < 8; ++k) {
      const float f = tile[(e8 + k) * 68 + q];
      const u16 h = f32_to_bf16(f);
      hi.us[k] = h;
      lo.us[k] = f32_to_bf16(f - bf16_to_f32(h));
    }
    const int dg = d0 + e8;
    const int chunkB = (q >> 5) * 64 + ((dg >> 3) & 1) * 32 + (q & 31);
    const size_t o = ((((size_t)b * 32 + bx) * 32 + (dg >> 4)) * 128 + chunkB) * 8;
    *(uint4*)(BpH + o) = hi.v4;
    *(uint4*)(BpL + o) = lo.v4;
  }
}

// ---------------- K1: fused GEMM (32x32x16) + softmax, 16 waves ----------------
__device__ __forceinline__ void gl16(const void* g, void* l) {
  __builtin_amdgcn_global_load_lds((const __attribute__((address_space(1))) void*)g,
                                   (__attribute__((address_space(3))) void*)l, 16, 0, 0);
}

#define WAITV0() asm volatile("s_waitcnt vmcnt(0)" ::: "memory")
#define SYNCPT() do { __builtin_amdgcn_s_barrier(); __builtin_amdgcn_sched_barrier(0); } while (0)

__global__ __launch_bounds__(1024, 4) void k_fused(const u16* __restrict__ UpH, const u16* __restrict__ UpL,
                                                   const u16* __restrict__ BpH, const u16* __restrict__ BpL,
                                                   const float* __restrict__ msq,
                                                   float* __restrict__ out) {
  __shared__ __align__(16) char sm[SM_SZ];
  const int tid = threadIdx.x;
  const int lane = tid & 63, wv = tid >> 6;       // wv 0..15
  const int l31 = lane & 31, lhi = lane >> 5;
  const int sw = wv;                              // wave owns s rows [sw*64, +64) = tiles 2sw, 2sw+1

  const int tgx = blockIdx.x;                     // 64-t group
  const int t00 = tgx * 64;
  const int bb = blockIdx.y;

  // ---- A: direct-from-global fragment bases (verified layout) ----
  // byte = ks*32768 + (2*sw + mt)*1024 + lane*16
  const char* const aH = (const char*)UpH + sw * 2048 + lane * 16;
  const char* const aL = (const char*)UpL + sw * 2048 + lane * 16;
  // ---- B: block panel (64KB hi + 64KB lo), staged whole in prologue ----
  const size_t bgBase = (size_t)(bb * 32 + tgx) * 65536;
  const char* const pBH = (const char*)BpH + bgBase;
  const char* const pBL = (const char*)BpL + bgBase;

  short8 ahE[2], alE[2], ahO[2], alO[2];          // A even/odd register dbuf (32 VGPR)

#define LD_A(AH, AL, KS) do { const size_t ko = (size_t)(KS) << 15;          \
    (AH)[0] = *(const short8*)(aH + ko);                                     \
    (AH)[1] = *(const short8*)(aH + ko + 1024);                              \
    (AL)[0] = *(const short8*)(aL + ko);                                     \
    (AL)[1] = *(const short8*)(aL + ko + 1024); } while (0)

  // ---- prologue: A(0)->E, A(1)->O, then stage full B panel ----
  LD_A(ahE, alE, 0);
  LD_A(ahO, alO, 1);
#pragma unroll
  for (int r = 0; r < 4; ++r) {
    const int off = (tid + r * 1024) * 16;        // [0, 65536)
    gl16(pBH + off, sm + off);
  }
#pragma unroll
  for (int r = 0; r < 4; ++r) {
    const int off = (tid + r * 1024) * 16;
    gl16(pBL + off, sm + B_LO_O + off);
  }

  f32x16 acc[2][2];
#pragma unroll
  for (int mt = 0; mt < 2; ++mt)
#pragma unroll
    for (int nt = 0; nt < 2; ++nt)
#pragma unroll
      for (int r = 0; r < 16; ++r)
        acc[mt][nt][r] = 0.f;

  WAITV0();
  SYNCPT();                                       // B panel resident; A(0),A(1) in regs

#define MM12(AH, AL, BH0, BH1, BL0, BL1) do {                                \
    __builtin_amdgcn_s_setprio(1);                                           \
    acc[0][0] = __builtin_amdgcn_mfma_f32_32x32x16_bf16((AH)[0], BH0, acc[0][0], 0, 0, 0); \
    acc[0][1] = __builtin_amdgcn_mfma_f32_32x32x16_bf16((AH)[0], BH1, acc[0][1], 0, 0, 0); \
    acc[1][0] = __builtin_amdgcn_mfma_f32_32x32x16_bf16((AH)[1], BH0, acc[1][0], 0, 0, 0); \
    acc[1][1] = __builtin_amdgcn_mfma_f32_32x32x16_bf16((AH)[1], BH1, acc[1][1], 0, 0, 0); \
    acc[0][0] = __builtin_amdgcn_mfma_f32_32x32x16_bf16((AH)[0], BL0, acc[0][0], 0, 0, 0); \
    acc[0][1] = __builtin_amdgcn_mfma_f32_32x32x16_bf16((AH)[0], BL1, acc[0][1], 0, 0, 0); \
    acc[1][0] = __builtin_amdgcn_mfma_f32_32x32x16_bf16((AH)[1], BL0, acc[1][0], 0, 0, 0); \
    acc[1][1] = __builtin_amdgcn_mfma_f32_32x32x16_bf16((AH)[1], BL1, acc[1][1], 0, 0, 0); \
    acc[0][0] = __builtin_amdgcn_mfma_f32_32x32x16_bf16((AL)[0], BH0, acc[0][0], 0, 0, 0); \
    acc[0][1] = __builtin_amdgcn_mfma_f32_32x32x16_bf16((AL)[0], BH1, acc[0][1], 0, 0, 0); \
    acc[1][0] = __builtin_amdgcn_mfma_f32_32x32x16_bf16((AL)[1], BH0, acc[1][0], 0, 0, 0); \
    acc[1][1] = __builtin_amdgcn_mfma_f32_32x32x16_bf16((AL)[1], BH1, acc[1][1], 0, 0, 0); \
    __builtin_amdgcn_s_setprio(0);                                           \
  } while (0)

  // ---- K-loop: barrier-free; A dbuf gives ~1 slab-round prefetch distance ----
#pragma unroll 1
  for (int k = 0; k < 32; k += 2) {
    // even slab k: consume E set
    {
      const int bo = k * 2048 + lane * 16;
      short8 bh0 = *(const short8*)(sm + bo);
      short8 bh1 = *(const short8*)(sm + bo + 1024);
      short8 bl0 = *(const short8*)(sm + B_LO_O + bo);
      short8 bl1 = *(const short8*)(sm + B_LO_O + bo + 1024);
      MM12(ahE, alE, bh0, bh1, bl0, bl1);
      const int kn = (k + 2 < 32) ? (k + 2) : 31;   // redundant tail load (dead)
      LD_A(ahE, alE, kn);                           // refill E: ~1 slab-round distance
    }
    // odd slab k+1: consume O set
    {
      const int bo = (k + 1) * 2048 + lane * 16;
      short8 bh0 = *(const short8*)(sm + bo);
      short8 bh1 = *(const short8*)(sm + bo + 1024);
      short8 bl0 = *(const short8*)(sm + B_LO_O + bo);
      short8 bl1 = *(const short8*)(sm + B_LO_O + bo + 1024);
      MM12(ahO, alO, bh0, bh1, bl0, bl1);
      const int kn = (k + 3 < 32) ? (k + 3) : 31;   // redundant tail load (dead)
      LD_A(ahO, alO, kn);                           // refill O
    }
  }

  // ---- epilogue: softmax over s, in registers ----
  // s = sw*64 + mt*32 + lhi*4 + q*8 + r (reg=q*4+r); t = t00 + nt*32 + l31.
  float* redM = (float*)(sm + REDM_O);   // [16][64]
  float* redS = (float*)(sm + REDS_O);
  float mx0 = -3.0e38f, mx1 = -3.0e38f;
#pragma unroll
  for (int mt = 0; mt < 2; ++mt) {
    const int sb = sw * 64 + mt * 32 + lhi * 4;
#pragma unroll
    for (int q = 0; q < 4; ++q) {
      const f32x4 mq = *(const f32x4*)(msq + sb + q * 8);
#pragma unroll
      for (int r = 0; r < 4; ++r) {
        const int reg = q * 4 + r;
        const float v0 = 2.f * acc[mt][0][reg] - mq[r];
        const float v1 = 2.f * acc[mt][1][reg] - mq[r];
        acc[mt][0][reg] = v0; acc[mt][1][reg] = v1;
        mx0 = fmaxf(mx0, v0); mx1 = fmaxf(mx1, v1);
      }
    }
  }
  mx0 = fmaxf(mx0, __shfl_xor(mx0, 32));
  mx1 = fmaxf(mx1, __shfl_xor(mx1, 32));
  if (lane < 32) { redM[wv * 64 + l31] = mx0; redM[wv * 64 + 32 + l31] = mx1; }
  __syncthreads();
  float M0 = redM[l31], M1 = redM[32 + l31];
#pragma unroll
  for (int w = 1; w < 16; ++w) {
    M0 = fmaxf(M0, redM[w * 64 + l31]);
    M1 = fmaxf(M1, redM[w * 64 + 32 + l31]);
  }
  float s0 = 0.f, s1 = 0.f;
#pragma unroll
  for (int mt = 0; mt < 2; ++mt)
#pragma unroll
    for (int reg = 0; reg < 16; ++reg) {
      const float e0 = __expf(acc[mt][0][reg] - M0);
      const float e1 = __expf(acc[mt][1][reg] - M1);
      acc[mt][0][reg] = e0; acc[mt][1][reg] = e1;
      s0 += e0; s1 += e1;
    }
  s0 += __shfl_xor(s0, 32);
  s1 += __shfl_xor(s1, 32);
  if (lane < 32) { redS[wv * 64 + l31] = s0; redS[wv * 64 + 32 + l31] = s1; }
  __syncthreads();
  float S0 = redS[l31], S1 = redS[32 + l31];
#pragma unroll
  for (int w = 1; w < 16; ++w) {
    S0 += redS[w * 64 + l31];
    S1 += redS[w * 64 + 32 + l31];
  }
  const float r0 = 1.0f / S0, r1 = 1.0f / S1;

  float* const outb = out + ((size_t)bb << 21);   // b * 1024 * 2048
  const int tc0 = t00 + l31, tc1 = t00 + 32 + l31;
#pragma unroll
  for (int mt = 0; mt < 2; ++mt) {
    const int sb = sw * 64 + mt * 32 + lhi * 4;
#pragma unroll
    for (int q = 0; q < 4; ++q)
#pragma unroll
      for (int r = 0; r < 4; ++r) {
        const int srow = sb + q * 8 + r;
        const int reg = q * 4 + r;
        outb[(size_t)srow * T_DIM + tc0] = acc[mt][0][reg] * r0;
        outb[(size_t)srow * T_DIM + tc1] = acc[mt][1][reg] * r1;
      }
  }
}

// ---------------- launch ----------------
extern "C" void kernel_launch(void* const* d_in, const int* in_sizes, int n_in,
                              void* d_out, int out_size, void* d_ws, size_t ws_size,
                              hipStream_t stream) {
  (void)in_sizes; (void)n_in; (void)out_size; (void)ws_size;
  const float* H = (const float*)d_in[0];
  const float* units = (const float*)d_in[1];
  float* out = (float*)d_out;
  char* ws = (char*)d_ws;
  u16* BpH = (u16*)(ws);
  u16* BpL = (u16*)(ws + 134217728);
  u16* UpH = (u16*)(ws + 268435456);
  u16* UpL = (u16*)(ws + 269484032);
  float* msq = (float*)(ws + 270532608);

  k_prep_units<<<dim3(S_DIM / 4), 256, 0, stream>>>(units, UpH, UpL, msq);
  k_prep_h<<<dim3(T_DIM / 64, DIM / 64, B_DIM), 256, 0, stream>>>(H, BpH, BpL);
  k_fused<<<dim3(T_DIM / 64, B_DIM), 1024, 0, stream>>>(UpH, UpL, BpH, BpL, msq, out);
}

// Round 17
// 576.143 us; speedup vs baseline: 1.0361x; 1.0215x over previous
//
#include <hip/hip_runtime.h>
#include <stdint.h>

// Problem: B=64, DIM=512, T=2048, S=1024.
// out[b][s][t] = softmax_s( 2*cross - msq[s] ),  cross = sum_d units[d][s]*H[b][d][t].
// R17 = R13's verified bf16 math/layouts with a deep-MLP K-loop:
//   A (64KB/slab16) + B (4KB/slab16) staged via global_load_lds into a 2-slot
//   LDS ring (68KB in flight during each slab's compute — vs R13's ~1-2KB of
//   register loads; Little's law says that was the plateau). 16 waves
//   (4/SIMD), wave 64s x 64t, acc 64 AGPR, frags just-in-time ds_read_b128.
//   One vmcnt(0)+barrier per slab (stage-to-wait distance ~1 slab >> latency).
// prep kernels + packs + epilogue VERBATIM from R13 (passing, absmax 0.0039).
// ws: BpH[0,128M) BpL[128M,256M) UpH(1M) UpL(1M) msq(4K) => ~258 MB.

typedef unsigned short u16;
typedef __attribute__((ext_vector_type(8))) short short8;    // 8 x bf16 (4 VGPR)
typedef __attribute__((ext_vector_type(4))) float f32x4;
typedef __attribute__((ext_vector_type(16))) float f32x16;   // 32x32 C/D

#define B_DIM 64
#define DIM   512
#define T_DIM 2048
#define S_DIM 1024

// k_fused LDS map: ring slot = Ah 32K | Al 32K | Bh 2K | Bl 2K = 69632 B
#define SLOT    69632
#define A_LO    32768
#define B_HI_O  65536
#define B_LO_O2 67584
#define REDM_O  139264       // 2*SLOT
#define REDS_O  143360
#define SM_SZ   147456

__device__ __forceinline__ u16 f32_to_bf16(float f) {
  uint32_t u = __float_as_uint(f);
  uint32_t r = u + 0x7FFFu + ((u >> 16) & 1u);   // RNE
  return (u16)(r >> 16);
}
__device__ __forceinline__ float bf16_to_f32(u16 h) {
  return __uint_as_float(((uint32_t)h) << 16);
}

// ---------------- K0a: units -> Upack hi/lo + msq (VERBATIM R13) ----------------
__global__ __launch_bounds__(256) void k_prep_units(const float* __restrict__ units,
                                                    u16* __restrict__ UpH, u16* __restrict__ UpL,
                                                    float* __restrict__ msq) {
  const int s0 = blockIdx.x * 4;
  const int tid = threadIdx.x;
  const int lane = tid & 63, wv = tid >> 6;
  float acc0 = 0.f, acc1 = 0.f, acc2 = 0.f, acc3 = 0.f;
#pragma unroll
  for (int j = 0; j < 2; ++j) {
    const int d = tid + j * 256;
    const float4 v = *(const float4*)(units + (size_t)d * S_DIM + s0);
    acc0 += v.x * v.x; acc1 += v.y * v.y; acc2 += v.z * v.z; acc3 += v.w * v.w;
    const int dbase = (d >> 4) * 16384 + ((d >> 3) & 1) * 256 + (d & 7);
    const float fv[4] = {v.x, v.y, v.z, v.w};
#pragma unroll
    for (int q = 0; q < 4; ++q) {
      const int s = s0 + q;
      const int idx = dbase + ((s >> 5) * 64 + (s & 31)) * 8;
      const u16 h = f32_to_bf16(fv[q]);
      UpH[idx] = h;
      UpL[idx] = f32_to_bf16(fv[q] - bf16_to_f32(h));
    }
  }
#pragma unroll
  for (int off = 1; off < 64; off <<= 1) {
    acc0 += __shfl_xor(acc0, off);
    acc1 += __shfl_xor(acc1, off);
    acc2 += __shfl_xor(acc2, off);
    acc3 += __shfl_xor(acc3, off);
  }
  __shared__ float part[4][4];
  if (lane == 0) { part[wv][0] = acc0; part[wv][1] = acc1; part[wv][2] = acc2; part[wv][3] = acc3; }
  __syncthreads();
  if (tid < 4) msq[s0 + tid] = part[0][tid] + part[1][tid] + part[2][tid] + part[3][tid];
}

// ---------------- K0b: H -> Bpack hi/lo (VERBATIM R13) ----------------
__global__ __launch_bounds__(256) void k_prep_h(const float* __restrict__ H,
                                                u16* __restrict__ BpH, u16* __restrict__ BpL) {
  __shared__ float tile[64 * 68];
  const int bx = blockIdx.x;                 // t-group (64 t)
  const int d0 = blockIdx.y * 64;
  const int b = blockIdx.z;
  const int t0 = bx * 64;
  const int tid = threadIdx.x;
#pragma unroll
  for (int j = 0; j < 4; ++j) {
    const int chunk = tid + j * 256;
    const int r = chunk >> 4, c4 = (chunk & 15) * 4;
    const float4 v = *(const float4*)(H + ((size_t)(b * DIM + d0 + r)) * T_DIM + t0 + c4);
    *(float4*)(&tile[r * 68 + c4]) = v;
  }
  __syncthreads();
#pragma unroll
  for (int j = 0; j < 2; ++j) {
    const int chunk = tid + j * 256;
    const int q = chunk >> 3, e8 = (chunk & 7) * 8;   // t-local q, d-local group e8
    union { u16 us[8]; uint4 v4; } hi, lo;
#pragma unroll
    for (int k = 0; k < 8; ++k) {
      const float f = tile[(e8 + k) * 68 + q];
      const u16 h = f32_to_bf16(f);
      hi.us[k] = h;
      lo.us[k] = f32_to_bf16(f - bf16_to_f32(h));
    }
    const int dg = d0 + e8;
    const int chunkB = (q >> 5) * 64 + ((dg >> 3) & 1) * 32 + (q & 31);
    const size_t o = ((((size_t)b * 32 + bx) * 32 + (dg >> 4)) * 128 + chunkB) * 8;
    *(uint4*)(BpH + o) = hi.v4;
    *(uint4*)(BpL + o) = lo.v4;
  }
}

// ---------------- K1: fused GEMM (32x32x16) + softmax, deep gl_lds ring ----------------
__device__ __forceinline__ void gl16(const void* g, void* l) {
  __builtin_amdgcn_global_load_lds((const __attribute__((address_space(1))) void*)g,
                                   (__attribute__((address_space(3))) void*)l, 16, 0, 0);
}

#define WAITV0() asm volatile("s_waitcnt vmcnt(0)" ::: "memory")
#define SYNCPT() do { __builtin_amdgcn_s_barrier(); __builtin_amdgcn_sched_barrier(0); } while (0)

__global__ __launch_bounds__(1024, 4) void k_fused(const u16* __restrict__ UpH, const u16* __restrict__ UpL,
                                                   const u16* __restrict__ BpH, const u16* __restrict__ BpL,
                                                   const float* __restrict__ msq,
                                                   float* __restrict__ out) {
  __shared__ __align__(16) char sm[SM_SZ];
  const int tid = threadIdx.x;
  const int lane = tid & 63, wv = tid >> 6;       // wv 0..15; wave owns s [wv*64, +64)
  const int l31 = lane & 31, lhi = lane >> 5;
  const int lane16 = lane * 16;
  const int sw = wv;

  const int tgx = blockIdx.x;                     // 64-t group
  const int t00 = tgx * 64;
  const int bb = blockIdx.y;

  const char* const pAh = (const char*)UpH;       // A slab16 ks: 32 KB @ ks*32768
  const char* const pAl = (const char*)UpL;
  const size_t bgBase = (size_t)(bb * 32 + tgx) * 65536;   // 64KB B panel (R13 pack)
  const char* const pBh = (const char*)BpH + bgBase;       // B slab16 ks: 2 KB @ ks*2048
  const char* const pBl = (const char*)BpL + bgBase;

  // stage slab KS into ring slot SLOTB: per wave 4 A-insts (+1 B-inst for wv<4)
#define STAGE(KS, SLOTB) do {                                                 \
    const size_t koA = (size_t)(KS) << 15;                                    \
    const int d0_ = (2 * wv) * 1024 + lane16;                                 \
    const int d1_ = d0_ + 1024;                                               \
    gl16(pAh + koA + d0_, sm + (SLOTB) + d0_);                                \
    gl16(pAh + koA + d1_, sm + (SLOTB) + d1_);                                \
    gl16(pAl + koA + d0_, sm + (SLOTB) + A_LO + d0_);                         \
    gl16(pAl + koA + d1_, sm + (SLOTB) + A_LO + d1_);                         \
    if (wv < 4) {                                                             \
      const char* src_ = (wv < 2) ? pBh : pBl;                                \
      const int reg_ = (wv < 2) ? B_HI_O : B_LO_O2;                           \
      const int bo_ = (wv & 1) * 1024 + lane16;                               \
      gl16(src_ + (size_t)(KS) * 2048 + bo_, sm + (SLOTB) + reg_ + bo_);      \
    }                                                                         \
  } while (0)

  f32x16 acc[2][2];
#pragma unroll
  for (int mt = 0; mt < 2; ++mt)
#pragma unroll
    for (int nt = 0; nt < 2; ++nt)
#pragma unroll
      for (int r = 0; r < 16; ++r)
        acc[mt][nt][r] = 0.f;

  // ---- prologue: stage slabs 0 and 1, drain, barrier ----
  STAGE(0, 0);
  STAGE(1, SLOT);
  WAITV0();
  SYNCPT();

  // ---- K-loop: 32 slab16s; 1 barrier + 1 vmcnt(0) per slab; 68 KB in flight ----
#pragma unroll 1
  for (int k = 0; k < 32; ++k) {
    const char* sl = sm + (k & 1) * SLOT;
    const int a0 = (2 * wv) * 1024 + lane16;
    short8 ah0 = *(const short8*)(sl + a0);
    short8 ah1 = *(const short8*)(sl + a0 + 1024);
    short8 al0 = *(const short8*)(sl + A_LO + a0);
    short8 al1 = *(const short8*)(sl + A_LO + a0 + 1024);
    short8 bh0 = *(const short8*)(sl + B_HI_O + lane16);
    short8 bh1 = *(const short8*)(sl + B_HI_O + 1024 + lane16);
    short8 bl0 = *(const short8*)(sl + B_LO_O2 + lane16);
    short8 bl1 = *(const short8*)(sl + B_LO_O2 + 1024 + lane16);
    __builtin_amdgcn_s_setprio(1);
    acc[0][0] = __builtin_amdgcn_mfma_f32_32x32x16_bf16(ah0, bh0, acc[0][0], 0, 0, 0);
    acc[0][1] = __builtin_amdgcn_mfma_f32_32x32x16_bf16(ah0, bh1, acc[0][1], 0, 0, 0);
    acc[1][0] = __builtin_amdgcn_mfma_f32_32x32x16_bf16(ah1, bh0, acc[1][0], 0, 0, 0);
    acc[1][1] = __builtin_amdgcn_mfma_f32_32x32x16_bf16(ah1, bh1, acc[1][1], 0, 0, 0);
    acc[0][0] = __builtin_amdgcn_mfma_f32_32x32x16_bf16(ah0, bl0, acc[0][0], 0, 0, 0);
    acc[0][1] = __builtin_amdgcn_mfma_f32_32x32x16_bf16(ah0, bl1, acc[0][1], 0, 0, 0);
    acc[1][0] = __builtin_amdgcn_mfma_f32_32x32x16_bf16(ah1, bl0, acc[1][0], 0, 0, 0);
    acc[1][1] = __builtin_amdgcn_mfma_f32_32x32x16_bf16(ah1, bl1, acc[1][1], 0, 0, 0);
    acc[0][0] = __builtin_amdgcn_mfma_f32_32x32x16_bf16(al0, bh0, acc[0][0], 0, 0, 0);
    acc[0][1] = __builtin_amdgcn_mfma_f32_32x32x16_bf16(al0, bh1, acc[0][1], 0, 0, 0);
    acc[1][0] = __builtin_amdgcn_mfma_f32_32x32x16_bf16(al1, bh0, acc[1][0], 0, 0, 0);
    acc[1][1] = __builtin_amdgcn_mfma_f32_32x32x16_bf16(al1, bh1, acc[1][1], 0, 0, 0);
    __builtin_amdgcn_s_setprio(0);
    WAITV0();                      // stage(k+1) landed (issued ~1 full slab ago)
    SYNCPT();                      // all waves done reading slot k; slot freed
    if (k + 2 < 32) STAGE(k + 2, (k & 1) * SLOT);
  }

  // ---- epilogue: softmax over s, in registers (VERBATIM R13 mapping) ----
  // s = sw*64 + mt*32 + lhi*4 + q*8 + r (reg=q*4+r); t = t00 + nt*32 + l31.
  float* redM = (float*)(sm + REDM_O);   // [16][64]
  float* redS = (float*)(sm + REDS_O);
  float mx0 = -3.0e38f, mx1 = -3.0e38f;
#pragma unroll
  for (int mt = 0; mt < 2; ++mt) {
    const int sb = sw * 64 + mt * 32 + lhi * 4;
#pragma unroll
    for (int q = 0; q < 4; ++q) {
      const f32x4 mq = *(const f32x4*)(msq + sb + q * 8);
#pragma unroll
      for (int r = 0; r < 4; ++r) {
        const int reg = q * 4 + r;
        const float v0 = 2.f * acc[mt][0][reg] - mq[r];
        const float v1 = 2.f * acc[mt][1][reg] - mq[r];
        acc[mt][0][reg] = v0; acc[mt][1][reg] = v1;
        mx0 = fmaxf(mx0, v0); mx1 = fmaxf(mx1, v1);
      }
    }
  }
  mx0 = fmaxf(mx0, __shfl_xor(mx0, 32));
  mx1 = fmaxf(mx1, __shfl_xor(mx1, 32));
  if (lane < 32) { redM[wv * 64 + l31] = mx0; redM[wv * 64 + 32 + l31] = mx1; }
  __syncthreads();
  float M0 = redM[l31], M1 = redM[32 + l31];
#pragma unroll
  for (int w = 1; w < 16; ++w) {
    M0 = fmaxf(M0, redM[w * 64 + l31]);
    M1 = fmaxf(M1, redM[w * 64 + 32 + l31]);
  }
  float s0 = 0.f, s1 = 0.f;
#pragma unroll
  for (int mt = 0; mt < 2; ++mt)
#pragma unroll
    for (int reg = 0; reg < 16; ++reg) {
      const float e0 = __expf(acc[mt][0][reg] - M0);
      const float e1 = __expf(acc[mt][1][reg] - M1);
      acc[mt][0][reg] = e0; acc[mt][1][reg] = e1;
      s0 += e0; s1 += e1;
    }
  s0 += __shfl_xor(s0, 32);
  s1 += __shfl_xor(s1, 32);
  if (lane < 32) { redS[wv * 64 + l31] = s0; redS[wv * 64 + 32 + l31] = s1; }
  __syncthreads();
  float S0 = redS[l31], S1 = redS[32 + l31];
#pragma unroll
  for (int w = 1; w < 16; ++w) {
    S0 += redS[w * 64 + l31];
    S1 += redS[w * 64 + 32 + l31];
  }
  const float r0 = 1.0f / S0, r1 = 1.0f / S1;

  float* const outb = out + ((size_t)bb << 21);   // b * 1024 * 2048
  const int tc0 = t00 + l31, tc1 = t00 + 32 + l31;
#pragma unroll
  for (int mt = 0; mt < 2; ++mt) {
    const int sb = sw * 64 + mt * 32 + lhi * 4;
#pragma unroll
    for (int q = 0; q < 4; ++q)
#pragma unroll
      for (int r = 0; r < 4; ++r) {
        const int srow = sb + q * 8 + r;
        const int reg = q * 4 + r;
        outb[(size_t)srow * T_DIM + tc0] = acc[mt][0][reg] * r0;
        outb[(size_t)srow * T_DIM + tc1] = acc[mt][1][reg] * r1;
      }
  }
}

// ---------------- launch ----------------
extern "C" void kernel_launch(void* const* d_in, const int* in_sizes, int n_in,
                              void* d_out, int out_size, void* d_ws, size_t ws_size,
                              hipStream_t stream) {
  (void)in_sizes; (void)n_in; (void)out_size; (void)ws_size;
  const float* H = (const float*)d_in[0];
  const float* units = (const float*)d_in[1];
  float* out = (float*)d_out;
  char* ws = (char*)d_ws;
  u16* BpH = (u16*)(ws);
  u16* BpL = (u16*)(ws + 134217728);
  u16* UpH = (u16*)(ws + 268435456);
  u16* UpL = (u16*)(ws + 269484032);
  float* msq = (float*)(ws + 270532608);

  k_prep_units<<<dim3(S_DIM / 4), 256, 0, stream>>>(units, UpH, UpL, msq);
  k_prep_h<<<dim3(T_DIM / 64, DIM / 64, B_DIM), 256, 0, stream>>>(H, BpH, BpL);
  k_fused<<<dim3(T_DIM / 64, B_DIM), 1024, 0, stream>>>(UpH, UpL, BpH, BpL, msq, out);
}